// Round 1
// baseline (47452.069 us; speedup 1.0000x reference)
//
#include <hip/hip_runtime.h>
#include <hip/hip_cooperative_groups.h>

namespace cg = cooperative_groups;

#define NB 4
#define NN 4096
#define NM 2304
#define NC 256
#define OUT_ELEMS 2359296  // 4*256*48*48

static constexpr float REG_INV = 0.1f;      // 1/REG
static constexpr float A_VAL = 1.0f / 4096.0f;
static constexpr float B_VAL = 1.0f / 2304.0f;
static constexpr float ALPHA_C = 0.001f;

__device__ __forceinline__ float bf2f(unsigned short h) {
  return __uint_as_float(((unsigned int)h) << 16);
}
__device__ __forceinline__ unsigned short f2bf(float f) {
  unsigned int u = __float_as_uint(f);
  unsigned int r = (u + 0x7FFFu + ((u >> 16) & 1u)) >> 16;  // RNE
  return (unsigned short)r;
}
__device__ __forceinline__ float waveSum(float s) {
#pragma unroll
  for (int off = 32; off > 0; off >>= 1) s += __shfl_xor(s, off);
  return s;
}

// x2[n] = sum_c X[n][c]^2 ; one wave per row
__global__ __launch_bounds__(256) void x2_kernel(const float* __restrict__ X,
                                                 float* __restrict__ x2) {
  int wid = threadIdx.x >> 6, lane = threadIdx.x & 63;
  int row = blockIdx.x * 4 + wid;  // grid 1024 -> 4096 rows
  float4 v = *(const float4*)(X + (size_t)row * NC + lane * 4);
  float s = v.x * v.x + v.y * v.y + v.z * v.z + v.w * v.w;
  s = waveSum(s);
  if (lane == 0) x2[row] = s;
}

// y2[b][m] = sum_c H[b][c][m]^2 ; thread per m (coalesced across m)
__global__ __launch_bounds__(256) void y2_kernel(const float* __restrict__ H,
                                                 float* __restrict__ y2) {
  int gid = blockIdx.x * 256 + threadIdx.x;  // grid 36 -> 9216
  int b = gid / NM, m = gid % NM;
  const float* p = H + (size_t)b * NC * NM + m;
  float s = 0.f;
#pragma unroll 4
  for (int c = 0; c < NC; ++c) {
    float t = p[(size_t)c * NM];
    s += t * t;
  }
  y2[gid] = s;
}

__global__ void init_u_kernel(float* __restrict__ u) {
  u[blockIdx.x * 256 + threadIdx.x] = A_VAL;  // grid 64 -> 16384
}

// G = X * H_b ; K = exp(-max(x2+y2-2G,0)/REG) -> write K (bf16) and KT (bf16)
__global__ __launch_bounds__(256) void cost_k_kernel(
    const float* __restrict__ X, const float* __restrict__ H,
    const float* __restrict__ x2, const float* __restrict__ y2,
    unsigned short* __restrict__ K, unsigned short* __restrict__ KT) {
  __shared__ float As[16][68];  // As[k][n]
  __shared__ float Bs[16][68];  // Bs[k][m]
  const int b = blockIdx.z;
  const int n0 = blockIdx.x * 64;
  const int m0 = blockIdx.y * 64;
  const int t = threadIdx.x;
  const int ty = t >> 4, tx = t & 15;
  float acc[4][4] = {};
  for (int c0 = 0; c0 < NC; c0 += 16) {
    {
      int n = t >> 2, kv = t & 3;
      float4 xv = *(const float4*)(X + (size_t)(n0 + n) * NC + c0 + kv * 4);
      As[kv * 4 + 0][n] = xv.x;
      As[kv * 4 + 1][n] = xv.y;
      As[kv * 4 + 2][n] = xv.z;
      As[kv * 4 + 3][n] = xv.w;
    }
    {
      int k = t >> 4, mv = t & 15;
      float4 hv = *(const float4*)(H + ((size_t)b * NC + c0 + k) * NM + m0 + mv * 4);
      *(float4*)&Bs[k][mv * 4] = hv;
    }
    __syncthreads();
#pragma unroll
    for (int k = 0; k < 16; ++k) {
      float4 a4 = *(const float4*)&As[k][ty * 4];
      float4 b4 = *(const float4*)&Bs[k][tx * 4];
      float a_[4] = {a4.x, a4.y, a4.z, a4.w};
      float b_[4] = {b4.x, b4.y, b4.z, b4.w};
#pragma unroll
      for (int i = 0; i < 4; ++i)
#pragma unroll
        for (int j = 0; j < 4; ++j) acc[i][j] += a_[i] * b_[j];
    }
    __syncthreads();
  }
  float kvals[4][4];
#pragma unroll
  for (int i = 0; i < 4; ++i) {
    int n = n0 + ty * 4 + i;
    float xx = x2[n];
#pragma unroll
    for (int j = 0; j < 4; ++j) {
      int m = m0 + tx * 4 + j;
      float cost = fmaxf(xx + y2[b * NM + m] - 2.0f * acc[i][j], 0.0f);
      kvals[i][j] = __expf(-cost * REG_INV);
    }
  }
#pragma unroll
  for (int i = 0; i < 4; ++i) {
    int n = n0 + ty * 4 + i;
    ushort4 kr;
    kr.x = f2bf(kvals[i][0]);
    kr.y = f2bf(kvals[i][1]);
    kr.z = f2bf(kvals[i][2]);
    kr.w = f2bf(kvals[i][3]);
    *(ushort4*)(K + ((size_t)b * NN + n) * NM + m0 + tx * 4) = kr;
  }
#pragma unroll
  for (int j = 0; j < 4; ++j) {
    int m = m0 + tx * 4 + j;
    ushort4 kt;
    kt.x = f2bf(kvals[0][j]);
    kt.y = f2bf(kvals[1][j]);
    kt.z = f2bf(kvals[2][j]);
    kt.w = f2bf(kvals[3][j]);
    *(ushort4*)(KT + ((size_t)b * NM + m) * NN + n0 + ty * 4) = kt;
  }
}

// 200 Sinkhorn iterations; 1024 blocks x 256 threads, cooperative.
// Block -> batch b = blk>>8, sub = blk&255.
// Pass A: block computes 9 columns m (via KT rows), u staged in LDS.
// Pass B: block computes 16 rows n (wave per row), v staged in LDS.
__global__ __launch_bounds__(256, 4) void sinkhorn_loop(
    const unsigned short* __restrict__ K, const unsigned short* __restrict__ KT,
    float* __restrict__ u, float* __restrict__ v) {
  cg::grid_group grid = cg::this_grid();
  __shared__ __align__(16) float stage[NN];
  __shared__ float wsum[4];
  const int t = threadIdx.x;
  const int lane = t & 63, wid = t >> 6;
  const int blk = blockIdx.x;
  const int b = blk >> 8;
  const int sub = blk & 255;
  const unsigned short* Kb = K + (size_t)b * NN * NM;
  const unsigned short* KTb = KT + (size_t)b * NM * NN;
  float* ub = u + b * NN;
  float* vb = v + b * NM;

#pragma unroll 1
  for (int it = 0; it < 200; ++it) {
    // ---- Pass A: v[m] = B_VAL / sum_n KT[m][n]*u[n]
    {
      float4* s4 = (float4*)stage;
      const float4* ug = (const float4*)ub;
#pragma unroll
      for (int i = 0; i < 4; ++i) s4[t + i * 256] = ug[t + i * 256];
      __syncthreads();
      const int m0 = sub * 9;
#pragma unroll 1
      for (int r = 0; r < 9; ++r) {
        const int m = m0 + r;
        const ushort4* krow = (const ushort4*)(KTb + (size_t)m * NN);
        float s = 0.f;
#pragma unroll
        for (int kk = 0; kk < 4; ++kk) {
          int j = t + kk * 256;
          ushort4 h = krow[j];
          float4 uu = s4[j];
          s += bf2f(h.x) * uu.x + bf2f(h.y) * uu.y + bf2f(h.z) * uu.z +
               bf2f(h.w) * uu.w;
        }
        s = waveSum(s);
        if (lane == 0) wsum[wid] = s;
        __syncthreads();
        if (t == 0) vb[m] = B_VAL / (wsum[0] + wsum[1] + wsum[2] + wsum[3]);
        __syncthreads();
      }
    }
    grid.sync();
    // ---- Pass B: u[n] = A_VAL / sum_m K[n][m]*v[m]
    {
      float4* s4 = (float4*)stage;
      const float4* vg = (const float4*)vb;
      for (int i = t; i < NM / 4; i += 256) s4[i] = vg[i];
      __syncthreads();
      const int n0 = sub * 16 + wid * 4;
#pragma unroll 1
      for (int r = 0; r < 4; ++r) {
        const int n = n0 + r;
        const ushort4* krow = (const ushort4*)(Kb + (size_t)n * NM);
        float s = 0.f;
#pragma unroll
        for (int kk = 0; kk < 9; ++kk) {
          int j = lane + kk * 64;
          ushort4 h = krow[j];
          float4 vv = s4[j];
          s += bf2f(h.x) * vv.x + bf2f(h.y) * vv.y + bf2f(h.z) * vv.z +
               bf2f(h.w) * vv.w;
        }
        s = waveSum(s);
        if (lane == 0) ub[n] = A_VAL / s;
      }
    }
    grid.sync();
  }
}

// XT[b][c][m] = v[m] * sum_n KT[m][n]*u[n]*X[n][c]   (output already transposed)
__global__ __launch_bounds__(256) void xspace_kernel(
    const unsigned short* __restrict__ KT, const float* __restrict__ X,
    const float* __restrict__ u, const float* __restrict__ v,
    float* __restrict__ XT) {
  __shared__ float As[16][68];  // As[k][m] = KT[m0+m][n0+k]
  __shared__ float Bs[16][68];  // Bs[k][c] = X[n0+k][c]*u[n0+k]
  const int b = blockIdx.z;
  const int m0 = blockIdx.x * 64;
  const int c0 = blockIdx.y * 64;
  const int t = threadIdx.x;
  const int ty = t >> 4, tx = t & 15;
  float acc[4][4] = {};
  for (int n0 = 0; n0 < NN; n0 += 16) {
    {
      int m = t >> 2, kv = t & 3;
      ushort4 a4 =
          *(const ushort4*)(KT + ((size_t)b * NM + m0 + m) * NN + n0 + kv * 4);
      As[kv * 4 + 0][m] = bf2f(a4.x);
      As[kv * 4 + 1][m] = bf2f(a4.y);
      As[kv * 4 + 2][m] = bf2f(a4.z);
      As[kv * 4 + 3][m] = bf2f(a4.w);
    }
    {
      int k = t >> 4, cv = t & 15;
      float uk = u[(size_t)b * NN + n0 + k];
      float4 xv = *(const float4*)(X + (size_t)(n0 + k) * NC + c0 + cv * 4);
      xv.x *= uk;
      xv.y *= uk;
      xv.z *= uk;
      xv.w *= uk;
      *(float4*)&Bs[k][cv * 4] = xv;
    }
    __syncthreads();
#pragma unroll
    for (int k = 0; k < 16; ++k) {
      float4 a4 = *(const float4*)&As[k][ty * 4];
      float4 b4 = *(const float4*)&Bs[k][tx * 4];
      float a_[4] = {a4.x, a4.y, a4.z, a4.w};
      float b_[4] = {b4.x, b4.y, b4.z, b4.w};
#pragma unroll
      for (int i = 0; i < 4; ++i)
#pragma unroll
        for (int j = 0; j < 4; ++j) acc[i][j] += a_[i] * b_[j];
    }
    __syncthreads();
  }
  float vm[4];
#pragma unroll
  for (int i = 0; i < 4; ++i) vm[i] = v[(size_t)b * NM + m0 + ty * 4 + i];
#pragma unroll
  for (int j = 0; j < 4; ++j) {
    int c = c0 + tx * 4 + j;
    float4 o;
    o.x = vm[0] * acc[0][j];
    o.y = vm[1] * acc[1][j];
    o.z = vm[2] * acc[2][j];
    o.w = vm[3] * acc[3][j];
    *(float4*)(XT + ((size_t)b * NC + c) * NM + m0 + ty * 4) = o;
  }
}

// out_aligned = H + alpha*XT ; out_feat = XT ; partial sums of (H-XT)^2
__global__ __launch_bounds__(256) void finalize_kernel(
    const float* __restrict__ H, const float* __restrict__ XT,
    float* __restrict__ out_aligned, float* __restrict__ out_feat,
    float* __restrict__ partials) {
  const int t = threadIdx.x;
  float s = 0.f;
  for (int i = blockIdx.x * 256 + t; i < OUT_ELEMS / 4; i += 1024 * 256) {
    float4 h = *(const float4*)(H + (size_t)i * 4);
    float4 x = *(const float4*)(XT + (size_t)i * 4);
    float4 o;
    o.x = h.x + ALPHA_C * x.x;
    o.y = h.y + ALPHA_C * x.y;
    o.z = h.z + ALPHA_C * x.z;
    o.w = h.w + ALPHA_C * x.w;
    *(float4*)(out_aligned + (size_t)i * 4) = o;
    out_feat[(size_t)i * 4 + 0] = x.x;  // dest misaligned by 1 float -> scalar
    out_feat[(size_t)i * 4 + 1] = x.y;
    out_feat[(size_t)i * 4 + 2] = x.z;
    out_feat[(size_t)i * 4 + 3] = x.w;
    float dx = h.x - x.x, dy = h.y - x.y, dz = h.z - x.z, dw = h.w - x.w;
    s += dx * dx + dy * dy + dz * dz + dw * dw;
  }
  s = waveSum(s);
  __shared__ float ws_[4];
  if ((t & 63) == 0) ws_[t >> 6] = s;
  __syncthreads();
  if (t == 0) partials[blockIdx.x] = ws_[0] + ws_[1] + ws_[2] + ws_[3];
}

__global__ __launch_bounds__(256) void lot_kernel(
    const float* __restrict__ partials, float* __restrict__ out_lot) {
  float s = 0.f;
  for (int i = threadIdx.x; i < 1024; i += 256) s += partials[i];
  s = waveSum(s);
  __shared__ float ws_[4];
  if ((threadIdx.x & 63) == 0) ws_[threadIdx.x >> 6] = s;
  __syncthreads();
  if (threadIdx.x == 0)
    out_lot[0] = (ws_[0] + ws_[1] + ws_[2] + ws_[3]) / (float)OUT_ELEMS;
}

extern "C" void kernel_launch(void* const* d_in, const int* in_sizes, int n_in,
                              void* d_out, int out_size, void* d_ws,
                              size_t ws_size, hipStream_t stream) {
  const float* X = (const float*)d_in[0];  // sc (4096,256)
  const float* H = (const float*)d_in[1];  // h_spot (4,256,48,48)
  float* out = (float*)d_out;
  char* ws = (char*)d_ws;

  // workspace layout (bytes)
  unsigned short* K = (unsigned short*)(ws);                // 75,497,472
  unsigned short* KT = (unsigned short*)(ws + 75497472);    // 75,497,472
  float* XT = (float*)(ws + 150994944);                     // 9,437,184
  float* x2 = (float*)(ws + 160432128);                     // 16,384
  float* y2 = (float*)(ws + 160448512);                     // 36,864
  float* u = (float*)(ws + 160485376);                      // 65,536
  float* v = (float*)(ws + 160550912);                      // 36,864
  float* partials = (float*)(ws + 160587776);               // 4,096
  if (ws_size < (size_t)160591872) return;

  x2_kernel<<<1024, 256, 0, stream>>>(X, x2);
  y2_kernel<<<36, 256, 0, stream>>>(H, y2);
  cost_k_kernel<<<dim3(64, 36, 4), 256, 0, stream>>>(X, H, x2, y2, K, KT);
  init_u_kernel<<<64, 256, 0, stream>>>(u);
  {
    void* args[] = {(void*)&K, (void*)&KT, (void*)&u, (void*)&v};
    hipLaunchCooperativeKernel((void*)sinkhorn_loop, dim3(1024), dim3(256),
                               args, 0, stream);
  }
  xspace_kernel<<<dim3(36, 4, 4), 256, 0, stream>>>(KT, X, u, v, XT);
  finalize_kernel<<<1024, 256, 0, stream>>>(H, XT, out, out + OUT_ELEMS + 1,
                                            partials);
  lot_kernel<<<1, 256, 0, stream>>>(partials, out + OUT_ELEMS);
}

// Round 2
// 7295.774 us; speedup vs baseline: 6.5040x; 6.5040x over previous
//
#include <hip/hip_runtime.h>

#define NB 4
#define NN 4096
#define NM 2304
#define NC 256
#define NCH 64         // n-chunks for v partials
#define OUT_ELEMS 2359296  // 4*256*48*48

static constexpr float REG_INV = 0.1f;      // 1/REG
static constexpr float A_VAL = 1.0f / 4096.0f;
static constexpr float B_VAL = 1.0f / 2304.0f;
static constexpr float ALPHA_C = 0.001f;

__device__ __forceinline__ float bf2f(unsigned short h) {
  return __uint_as_float(((unsigned int)h) << 16);
}
__device__ __forceinline__ unsigned short f2bf(float f) {
  unsigned int u = __float_as_uint(f);
  unsigned int r = (u + 0x7FFFu + ((u >> 16) & 1u)) >> 16;  // RNE
  return (unsigned short)r;
}
__device__ __forceinline__ float waveSum(float s) {
#pragma unroll
  for (int off = 32; off > 0; off >>= 1) s += __shfl_xor(s, off);
  return s;
}

// x2[n] = sum_c X[n][c]^2 ; one wave per row
__global__ __launch_bounds__(256) void x2_kernel(const float* __restrict__ X,
                                                 float* __restrict__ x2) {
  int wid = threadIdx.x >> 6, lane = threadIdx.x & 63;
  int row = blockIdx.x * 4 + wid;  // grid 1024 -> 4096 rows
  float4 v = *(const float4*)(X + (size_t)row * NC + lane * 4);
  float s = v.x * v.x + v.y * v.y + v.z * v.z + v.w * v.w;
  s = waveSum(s);
  if (lane == 0) x2[row] = s;
}

// y2[b][m] = sum_c H[b][c][m]^2 ; thread per m (coalesced across m)
__global__ __launch_bounds__(256) void y2_kernel(const float* __restrict__ H,
                                                 float* __restrict__ y2) {
  int gid = blockIdx.x * 256 + threadIdx.x;  // grid 36 -> 9216
  int b = gid / NM, m = gid % NM;
  const float* p = H + (size_t)b * NC * NM + m;
  float s = 0.f;
#pragma unroll 4
  for (int c = 0; c < NC; ++c) {
    float t = p[(size_t)c * NM];
    s += t * t;
  }
  y2[gid] = s;
}

__global__ void init_u_kernel(float* __restrict__ u) {
  u[blockIdx.x * 256 + threadIdx.x] = A_VAL;  // grid 64 -> 16384
}

// G = X * H_b ; K = exp(-max(x2+y2-2G,0)/REG) -> write K (bf16) row-major only
__global__ __launch_bounds__(256) void cost_k_kernel(
    const float* __restrict__ X, const float* __restrict__ H,
    const float* __restrict__ x2, const float* __restrict__ y2,
    unsigned short* __restrict__ K) {
  __shared__ float As[16][68];  // As[k][n]
  __shared__ float Bs[16][68];  // Bs[k][m]
  const int b = blockIdx.z;
  const int n0 = blockIdx.x * 64;
  const int m0 = blockIdx.y * 64;
  const int t = threadIdx.x;
  const int ty = t >> 4, tx = t & 15;
  float acc[4][4] = {};
  for (int c0 = 0; c0 < NC; c0 += 16) {
    {
      int n = t >> 2, kv = t & 3;
      float4 xv = *(const float4*)(X + (size_t)(n0 + n) * NC + c0 + kv * 4);
      As[kv * 4 + 0][n] = xv.x;
      As[kv * 4 + 1][n] = xv.y;
      As[kv * 4 + 2][n] = xv.z;
      As[kv * 4 + 3][n] = xv.w;
    }
    {
      int k = t >> 4, mv = t & 15;
      float4 hv = *(const float4*)(H + ((size_t)b * NC + c0 + k) * NM + m0 + mv * 4);
      *(float4*)&Bs[k][mv * 4] = hv;
    }
    __syncthreads();
#pragma unroll
    for (int k = 0; k < 16; ++k) {
      float4 a4 = *(const float4*)&As[k][ty * 4];
      float4 b4 = *(const float4*)&Bs[k][tx * 4];
      float a_[4] = {a4.x, a4.y, a4.z, a4.w};
      float b_[4] = {b4.x, b4.y, b4.z, b4.w};
#pragma unroll
      for (int i = 0; i < 4; ++i)
#pragma unroll
        for (int j = 0; j < 4; ++j) acc[i][j] += a_[i] * b_[j];
    }
    __syncthreads();
  }
#pragma unroll
  for (int i = 0; i < 4; ++i) {
    int n = n0 + ty * 4 + i;
    float xx = x2[n];
    ushort4 kr;
    float kv0 = __expf(-fmaxf(xx + y2[b * NM + m0 + tx * 4 + 0] - 2.0f * acc[i][0], 0.0f) * REG_INV);
    float kv1 = __expf(-fmaxf(xx + y2[b * NM + m0 + tx * 4 + 1] - 2.0f * acc[i][1], 0.0f) * REG_INV);
    float kv2 = __expf(-fmaxf(xx + y2[b * NM + m0 + tx * 4 + 2] - 2.0f * acc[i][2], 0.0f) * REG_INV);
    float kv3 = __expf(-fmaxf(xx + y2[b * NM + m0 + tx * 4 + 3] - 2.0f * acc[i][3], 0.0f) * REG_INV);
    kr.x = f2bf(kv0);
    kr.y = f2bf(kv1);
    kr.z = f2bf(kv2);
    kr.w = f2bf(kv3);
    *(ushort4*)(K + ((size_t)b * NN + n) * NM + m0 + tx * 4) = kr;
  }
}

// vpart[b][ch][m] = sum_{n in chunk ch} K[b][n][m] * u[b][n]
// grid (9, 64, 4), block 256. Lane owns 4 consecutive m; wave w strides n by 4.
__global__ __launch_bounds__(256) void vpart_kernel(
    const unsigned short* __restrict__ K, const float* __restrict__ u,
    float* __restrict__ part) {
  const int mg = blockIdx.x;  // 0..8  (m-group of 256)
  const int ch = blockIdx.y;  // 0..63 (n-chunk of 64)
  const int b = blockIdx.z;
  const int t = threadIdx.x, l = t & 63, w = t >> 6;
  __shared__ float uS[64];
  __shared__ __align__(16) float red[4][64][4];
  if (t < 64) uS[t] = u[b * NN + ch * 64 + t];
  __syncthreads();
  const unsigned short* Kp =
      K + ((size_t)b * NN + ch * 64) * NM + mg * 256 + l * 4;
  float4 acc = {0.f, 0.f, 0.f, 0.f};
#pragma unroll
  for (int i = 0; i < 16; ++i) {
    int n = i * 4 + w;
    ushort4 kk = *(const ushort4*)(Kp + (size_t)n * NM);
    float uu = uS[n];
    acc.x += bf2f(kk.x) * uu;
    acc.y += bf2f(kk.y) * uu;
    acc.z += bf2f(kk.z) * uu;
    acc.w += bf2f(kk.w) * uu;
  }
  *(float4*)red[w][l] = acc;
  __syncthreads();
  if (w == 0) {
    float4 a0 = *(float4*)red[0][l];
    float4 a1 = *(float4*)red[1][l];
    float4 a2 = *(float4*)red[2][l];
    float4 a3 = *(float4*)red[3][l];
    float4 o;
    o.x = a0.x + a1.x + a2.x + a3.x;
    o.y = a0.y + a1.y + a2.y + a3.y;
    o.z = a0.z + a1.z + a2.z + a3.z;
    o.w = a0.w + a1.w + a2.w + a3.w;
    *(float4*)(part + ((size_t)b * NCH + ch) * NM + mg * 256 + l * 4) = o;
  }
}

// v[b][m] = B_VAL / sum_ch part[b][ch][m] ; grid 36, block 256
__global__ __launch_bounds__(256) void vfin_kernel(
    const float* __restrict__ part, float* __restrict__ v) {
  int gid = blockIdx.x * 256 + threadIdx.x;  // 0..9215
  int b = gid / NM, m = gid - b * NM;
  float s = 0.f;
#pragma unroll 8
  for (int ch = 0; ch < NCH; ++ch) s += part[((size_t)b * NCH + ch) * NM + m];
  v[gid] = B_VAL / s;
}

// u[b][n] = A_VAL / sum_m K[b][n][m]*v[b][m] ; wave per row, grid (1024,4)
__global__ __launch_bounds__(256) void uker_kernel(
    const unsigned short* __restrict__ K, const float* __restrict__ v,
    float* __restrict__ u) {
  const int b = blockIdx.y;
  const int t = threadIdx.x, l = t & 63, w = t >> 6;
  __shared__ __align__(16) float vS[NM];
  for (int i = t; i < NM; i += 256) vS[i] = v[b * NM + i];
  __syncthreads();
  const int n = blockIdx.x * 4 + w;
  const unsigned short* Kp = K + ((size_t)b * NN + n) * NM + l * 4;
  float s = 0.f;
#pragma unroll
  for (int kk = 0; kk < 9; ++kk) {
    ushort4 h = *(const ushort4*)(Kp + kk * 256);
    float4 vv = *(const float4*)&vS[kk * 256 + l * 4];
    s += bf2f(h.x) * vv.x + bf2f(h.y) * vv.y + bf2f(h.z) * vv.z +
         bf2f(h.w) * vv.w;
  }
  s = waveSum(s);
  if (l == 0) u[b * NN + n] = A_VAL / s;
}

// XT[b][c][m] = v[m] * sum_n K[n][m]*u[n]*X[n][c]   (output already transposed)
__global__ __launch_bounds__(256) void xspace_kernel(
    const unsigned short* __restrict__ K, const float* __restrict__ X,
    const float* __restrict__ u, const float* __restrict__ v,
    float* __restrict__ XT) {
  __shared__ float As[16][68];  // As[k][m] = K[n0+k][m0+m]
  __shared__ float Bs[16][68];  // Bs[k][c] = X[n0+k][c]*u[n0+k]
  const int b = blockIdx.z;
  const int m0 = blockIdx.x * 64;
  const int c0 = blockIdx.y * 64;
  const int t = threadIdx.x;
  const int ty = t >> 4, tx = t & 15;
  float acc[4][4] = {};
  for (int n0 = 0; n0 < NN; n0 += 16) {
    {
      int r = t >> 4, q = t & 15;  // row 0..15, m-quarter 0..15
      ushort4 a4 =
          *(const ushort4*)(K + ((size_t)b * NN + n0 + r) * NM + m0 + q * 4);
      As[r][q * 4 + 0] = bf2f(a4.x);
      As[r][q * 4 + 1] = bf2f(a4.y);
      As[r][q * 4 + 2] = bf2f(a4.z);
      As[r][q * 4 + 3] = bf2f(a4.w);
    }
    {
      int k = t >> 4, cv = t & 15;
      float uk = u[(size_t)b * NN + n0 + k];
      float4 xv = *(const float4*)(X + (size_t)(n0 + k) * NC + c0 + cv * 4);
      xv.x *= uk;
      xv.y *= uk;
      xv.z *= uk;
      xv.w *= uk;
      *(float4*)&Bs[k][cv * 4] = xv;
    }
    __syncthreads();
#pragma unroll
    for (int k = 0; k < 16; ++k) {
      float4 a4 = *(const float4*)&As[k][ty * 4];
      float4 b4 = *(const float4*)&Bs[k][tx * 4];
      float a_[4] = {a4.x, a4.y, a4.z, a4.w};
      float b_[4] = {b4.x, b4.y, b4.z, b4.w};
#pragma unroll
      for (int i = 0; i < 4; ++i)
#pragma unroll
        for (int j = 0; j < 4; ++j) acc[i][j] += a_[i] * b_[j];
    }
    __syncthreads();
  }
  float vm[4];
#pragma unroll
  for (int i = 0; i < 4; ++i) vm[i] = v[(size_t)b * NM + m0 + ty * 4 + i];
#pragma unroll
  for (int j = 0; j < 4; ++j) {
    int c = c0 + tx * 4 + j;
    float4 o;
    o.x = vm[0] * acc[0][j];
    o.y = vm[1] * acc[1][j];
    o.z = vm[2] * acc[2][j];
    o.w = vm[3] * acc[3][j];
    *(float4*)(XT + ((size_t)b * NC + c) * NM + m0 + ty * 4) = o;
  }
}

// out_aligned = H + alpha*XT ; out_feat = XT ; partial sums of (H-XT)^2
__global__ __launch_bounds__(256) void finalize_kernel(
    const float* __restrict__ H, const float* __restrict__ XT,
    float* __restrict__ out_aligned, float* __restrict__ out_feat,
    float* __restrict__ partials) {
  const int t = threadIdx.x;
  float s = 0.f;
  for (int i = blockIdx.x * 256 + t; i < OUT_ELEMS / 4; i += 1024 * 256) {
    float4 h = *(const float4*)(H + (size_t)i * 4);
    float4 x = *(const float4*)(XT + (size_t)i * 4);
    float4 o;
    o.x = h.x + ALPHA_C * x.x;
    o.y = h.y + ALPHA_C * x.y;
    o.z = h.z + ALPHA_C * x.z;
    o.w = h.w + ALPHA_C * x.w;
    *(float4*)(out_aligned + (size_t)i * 4) = o;
    out_feat[(size_t)i * 4 + 0] = x.x;  // dest misaligned by 1 float -> scalar
    out_feat[(size_t)i * 4 + 1] = x.y;
    out_feat[(size_t)i * 4 + 2] = x.z;
    out_feat[(size_t)i * 4 + 3] = x.w;
    float dx = h.x - x.x, dy = h.y - x.y, dz = h.z - x.z, dw = h.w - x.w;
    s += dx * dx + dy * dy + dz * dz + dw * dw;
  }
  s = waveSum(s);
  __shared__ float ws_[4];
  if ((t & 63) == 0) ws_[t >> 6] = s;
  __syncthreads();
  if (t == 0) partials[blockIdx.x] = ws_[0] + ws_[1] + ws_[2] + ws_[3];
}

__global__ __launch_bounds__(256) void lot_kernel(
    const float* __restrict__ partials, float* __restrict__ out_lot) {
  float s = 0.f;
  for (int i = threadIdx.x; i < 1024; i += 256) s += partials[i];
  s = waveSum(s);
  __shared__ float ws_[4];
  if ((threadIdx.x & 63) == 0) ws_[threadIdx.x >> 6] = s;
  __syncthreads();
  if (threadIdx.x == 0)
    out_lot[0] = (ws_[0] + ws_[1] + ws_[2] + ws_[3]) / (float)OUT_ELEMS;
}

extern "C" void kernel_launch(void* const* d_in, const int* in_sizes, int n_in,
                              void* d_out, int out_size, void* d_ws,
                              size_t ws_size, hipStream_t stream) {
  const float* X = (const float*)d_in[0];  // sc (4096,256)
  const float* H = (const float*)d_in[1];  // h_spot (4,256,48,48)
  float* out = (float*)d_out;
  char* ws = (char*)d_ws;

  // workspace layout (bytes)
  unsigned short* K = (unsigned short*)(ws);       // 75,497,472
  float* XT = (float*)(ws + 75497472);             // 9,437,184
  float* x2 = (float*)(ws + 84934656);             // 16,384
  float* y2 = (float*)(ws + 84951040);             // 36,864
  float* u = (float*)(ws + 84987904);              // 65,536
  float* v = (float*)(ws + 85053440);              // 36,864
  float* part = (float*)(ws + 85090304);           // 2,359,296
  float* partials = (float*)(ws + 87449600);       // 4,096
  if (ws_size < (size_t)87453696) return;

  x2_kernel<<<1024, 256, 0, stream>>>(X, x2);
  y2_kernel<<<36, 256, 0, stream>>>(H, y2);
  cost_k_kernel<<<dim3(64, 36, 4), 256, 0, stream>>>(X, H, x2, y2, K);
  init_u_kernel<<<64, 256, 0, stream>>>(u);
  for (int it = 0; it < 200; ++it) {
    vpart_kernel<<<dim3(9, NCH, 4), 256, 0, stream>>>(K, u, part);
    vfin_kernel<<<36, 256, 0, stream>>>(part, v);
    uker_kernel<<<dim3(1024, 4), 256, 0, stream>>>(K, v, u);
  }
  xspace_kernel<<<dim3(36, 4, 4), 256, 0, stream>>>(K, X, u, v, XT);
  finalize_kernel<<<1024, 256, 0, stream>>>(H, XT, out, out + OUT_ELEMS + 1,
                                            partials);
  lot_kernel<<<1, 256, 0, stream>>>(partials, out + OUT_ELEMS);
}

// Round 3
// 2271.752 us; speedup vs baseline: 20.8879x; 3.2115x over previous
//
#include <hip/hip_runtime.h>

#define NN 4096
#define NM 2304
#define NC 256
#define OUT_ELEMS 2359296  // 4*256*48*48

static constexpr float REG_INV = 0.1f;      // 1/REG
static constexpr float A_VAL = 1.0f / 4096.0f;
static constexpr float B_VAL = 1.0f / 2304.0f;
static constexpr float ALPHA_C = 0.001f;
static constexpr float EPS_CONV = 1e-6f;

__device__ __forceinline__ float bf2f(unsigned short h) {
  return __uint_as_float(((unsigned int)h) << 16);
}
__device__ __forceinline__ unsigned short f2bf(float f) {
  unsigned int u = __float_as_uint(f);
  unsigned int r = (u + 0x7FFFu + ((u >> 16) & 1u)) >> 16;  // RNE
  return (unsigned short)r;
}
__device__ __forceinline__ float waveSum(float s) {
#pragma unroll
  for (int off = 32; off > 0; off >>= 1) s += __shfl_xor(s, off);
  return s;
}

// x2[n] = sum_c X[n][c]^2 ; one wave per row
__global__ __launch_bounds__(256) void x2_kernel(const float* __restrict__ X,
                                                 float* __restrict__ x2) {
  int wid = threadIdx.x >> 6, lane = threadIdx.x & 63;
  int row = blockIdx.x * 4 + wid;  // grid 1024 -> 4096 rows
  float4 v = *(const float4*)(X + (size_t)row * NC + lane * 4);
  float s = v.x * v.x + v.y * v.y + v.z * v.z + v.w * v.w;
  s = waveSum(s);
  if (lane == 0) x2[row] = s;
}

// y2[b][m] = sum_c H[b][c][m]^2 ; thread per m (coalesced across m)
__global__ __launch_bounds__(256) void y2_kernel(const float* __restrict__ H,
                                                 float* __restrict__ y2) {
  int gid = blockIdx.x * 256 + threadIdx.x;  // grid 36 -> 9216
  int b = gid / NM, m = gid % NM;
  const float* p = H + (size_t)b * NC * NM + m;
  float s = 0.f;
#pragma unroll 4
  for (int c = 0; c < NC; ++c) {
    float t = p[(size_t)c * NM];
    s += t * t;
  }
  y2[gid] = s;
}

// u = A_VAL (16384), vsum[parity 0] = 0 (9216), notconv[2][4] = 1
__global__ __launch_bounds__(256) void init_kernel(float* __restrict__ u,
                                                   float* __restrict__ vsum0,
                                                   int* __restrict__ notconv) {
  int gid = blockIdx.x * 256 + threadIdx.x;  // grid 64 -> 16384
  u[gid] = A_VAL;
  if (gid < NM * 4) vsum0[gid] = 0.f;
  if (gid < 8) notconv[gid] = 1;
}

// G = X * H_b ; K = exp(-max(x2+y2-2G,0)/REG) -> write K (bf16) row-major only
__global__ __launch_bounds__(256) void cost_k_kernel(
    const float* __restrict__ X, const float* __restrict__ H,
    const float* __restrict__ x2, const float* __restrict__ y2,
    unsigned short* __restrict__ K) {
  __shared__ float As[16][68];  // As[k][n]
  __shared__ float Bs[16][68];  // Bs[k][m]
  const int b = blockIdx.z;
  const int n0 = blockIdx.x * 64;
  const int m0 = blockIdx.y * 64;
  const int t = threadIdx.x;
  const int ty = t >> 4, tx = t & 15;
  float acc[4][4] = {};
  for (int c0 = 0; c0 < NC; c0 += 16) {
    {
      int n = t >> 2, kv = t & 3;
      float4 xv = *(const float4*)(X + (size_t)(n0 + n) * NC + c0 + kv * 4);
      As[kv * 4 + 0][n] = xv.x;
      As[kv * 4 + 1][n] = xv.y;
      As[kv * 4 + 2][n] = xv.z;
      As[kv * 4 + 3][n] = xv.w;
    }
    {
      int k = t >> 4, mv = t & 15;
      float4 hv = *(const float4*)(H + ((size_t)b * NC + c0 + k) * NM + m0 + mv * 4);
      *(float4*)&Bs[k][mv * 4] = hv;
    }
    __syncthreads();
#pragma unroll
    for (int k = 0; k < 16; ++k) {
      float4 a4 = *(const float4*)&As[k][ty * 4];
      float4 b4 = *(const float4*)&Bs[k][tx * 4];
      float a_[4] = {a4.x, a4.y, a4.z, a4.w};
      float b_[4] = {b4.x, b4.y, b4.z, b4.w};
#pragma unroll
      for (int i = 0; i < 4; ++i)
#pragma unroll
        for (int j = 0; j < 4; ++j) acc[i][j] += a_[i] * b_[j];
    }
    __syncthreads();
  }
#pragma unroll
  for (int i = 0; i < 4; ++i) {
    int n = n0 + ty * 4 + i;
    float xx = x2[n];
    ushort4 kr;
    kr.x = f2bf(__expf(-fmaxf(xx + y2[b * NM + m0 + tx * 4 + 0] - 2.0f * acc[i][0], 0.0f) * REG_INV));
    kr.y = f2bf(__expf(-fmaxf(xx + y2[b * NM + m0 + tx * 4 + 1] - 2.0f * acc[i][1], 0.0f) * REG_INV));
    kr.z = f2bf(__expf(-fmaxf(xx + y2[b * NM + m0 + tx * 4 + 2] - 2.0f * acc[i][2], 0.0f) * REG_INV));
    kr.w = f2bf(__expf(-fmaxf(xx + y2[b * NM + m0 + tx * 4 + 3] - 2.0f * acc[i][3], 0.0f) * REG_INV));
    *(ushort4*)(K + ((size_t)b * NN + n) * NM + m0 + tx * 4) = kr;
  }
}

// vsumC[b][m] += sum_{n in chunk} K[b][n][m] * u[b][n]  (atomic accumulate)
// grid (9, 64, 4), block 256. Lane owns 4 consecutive m; wave w strides n by 4.
// Also: unconditionally zeroes this iteration's notconv slot (sticky-done safe),
// then exits early if batch already converged.
__global__ __launch_bounds__(256) void vpart_kernel(
    const unsigned short* __restrict__ K, const float* __restrict__ u,
    float* __restrict__ vsumC, const int* __restrict__ ncPrev,
    int* __restrict__ ncZero) {
  const int b = blockIdx.z;
  if (blockIdx.x == 0 && blockIdx.y == 0 && threadIdx.x == 0) ncZero[b] = 0;
  if (ncPrev[b] == 0) return;  // batch converged: keep u,v,vsum untouched
  const int mg = blockIdx.x;  // 0..8  (m-group of 256)
  const int ch = blockIdx.y;  // 0..63 (n-chunk of 64)
  const int t = threadIdx.x, l = t & 63, w = t >> 6;
  __shared__ float uS[64];
  __shared__ __align__(16) float red[4][64][4];
  if (t < 64) uS[t] = u[b * NN + ch * 64 + t];
  __syncthreads();
  const unsigned short* Kp =
      K + ((size_t)b * NN + ch * 64) * NM + mg * 256 + l * 4;
  float4 acc = {0.f, 0.f, 0.f, 0.f};
#pragma unroll
  for (int i = 0; i < 16; ++i) {
    int n = i * 4 + w;
    ushort4 kk = *(const ushort4*)(Kp + (size_t)n * NM);
    float uu = uS[n];
    acc.x += bf2f(kk.x) * uu;
    acc.y += bf2f(kk.y) * uu;
    acc.z += bf2f(kk.z) * uu;
    acc.w += bf2f(kk.w) * uu;
  }
  *(float4*)red[w][l] = acc;
  __syncthreads();
  if (w == 0) {
    float4 a0 = *(float4*)red[0][l];
    float4 a1 = *(float4*)red[1][l];
    float4 a2 = *(float4*)red[2][l];
    float4 a3 = *(float4*)red[3][l];
    float* dst = vsumC + (size_t)b * NM + mg * 256 + l * 4;
    atomicAdd(dst + 0, a0.x + a1.x + a2.x + a3.x);
    atomicAdd(dst + 1, a0.y + a1.y + a2.y + a3.y);
    atomicAdd(dst + 2, a0.z + a1.z + a2.z + a3.z);
    atomicAdd(dst + 3, a0.w + a1.w + a2.w + a3.w);
  }
}

// u[b][n] = A_VAL / sum_m K[b][n][m] * (B_VAL/vsumC[b][m])
// grid (256, 4), block 256: 16 rows per block, 4 rows per wave.
// Folds v-finalize (v = B/vsum), writes v (block x==0), zeroes next vsum
// (block x==1), and sets notconv when any row still changing.
__global__ __launch_bounds__(256) void uker_kernel(
    const unsigned short* __restrict__ K, const float* __restrict__ vsumC,
    float* __restrict__ vsumN, float* __restrict__ u, float* __restrict__ v,
    const int* __restrict__ ncPrev, int* __restrict__ ncSet) {
  const int b = blockIdx.y;
  if (ncPrev[b] == 0) return;
  const int t = threadIdx.x, l = t & 63, w = t >> 6;
  __shared__ __align__(16) float vS[NM];
  for (int i = t; i < NM; i += 256) {
    float val = B_VAL / vsumC[(size_t)b * NM + i];
    vS[i] = val;
    if (blockIdx.x == 0) v[b * NM + i] = val;
    if (blockIdx.x == 1) vsumN[(size_t)b * NM + i] = 0.f;
  }
  __syncthreads();
  float4 vv[9];
#pragma unroll
  for (int kk = 0; kk < 9; ++kk)
    vv[kk] = *(const float4*)&vS[kk * 256 + l * 4];
#pragma unroll
  for (int r = 0; r < 4; ++r) {
    const int n = blockIdx.x * 16 + w * 4 + r;
    const unsigned short* Kp = K + ((size_t)b * NN + n) * NM + l * 4;
    float s = 0.f;
#pragma unroll
    for (int kk = 0; kk < 9; ++kk) {
      ushort4 h = *(const ushort4*)(Kp + kk * 256);
      s += bf2f(h.x) * vv[kk].x + bf2f(h.y) * vv[kk].y +
           bf2f(h.z) * vv[kk].z + bf2f(h.w) * vv[kk].w;
    }
    s = waveSum(s);
    if (l == 0) {
      float uo = u[b * NN + n];
      float un = A_VAL / s;
      u[b * NN + n] = un;
      if (fabsf(un - uo) > EPS_CONV * uo) ncSet[b] = 1;
    }
  }
}

// XT[b][c][m] = v[m] * sum_n K[n][m]*u[n]*X[n][c]   (output already transposed)
__global__ __launch_bounds__(256) void xspace_kernel(
    const unsigned short* __restrict__ K, const float* __restrict__ X,
    const float* __restrict__ u, const float* __restrict__ v,
    float* __restrict__ XT) {
  __shared__ float As[16][68];  // As[k][m] = K[n0+k][m0+m]
  __shared__ float Bs[16][68];  // Bs[k][c] = X[n0+k][c]*u[n0+k]
  const int b = blockIdx.z;
  const int m0 = blockIdx.x * 64;
  const int c0 = blockIdx.y * 64;
  const int t = threadIdx.x;
  const int ty = t >> 4, tx = t & 15;
  float acc[4][4] = {};
  for (int n0 = 0; n0 < NN; n0 += 16) {
    {
      int r = t >> 4, q = t & 15;  // row 0..15, m-quarter 0..15
      ushort4 a4 =
          *(const ushort4*)(K + ((size_t)b * NN + n0 + r) * NM + m0 + q * 4);
      As[r][q * 4 + 0] = bf2f(a4.x);
      As[r][q * 4 + 1] = bf2f(a4.y);
      As[r][q * 4 + 2] = bf2f(a4.z);
      As[r][q * 4 + 3] = bf2f(a4.w);
    }
    {
      int k = t >> 4, cv = t & 15;
      float uk = u[(size_t)b * NN + n0 + k];
      float4 xv = *(const float4*)(X + (size_t)(n0 + k) * NC + c0 + cv * 4);
      xv.x *= uk;
      xv.y *= uk;
      xv.z *= uk;
      xv.w *= uk;
      *(float4*)&Bs[k][cv * 4] = xv;
    }
    __syncthreads();
#pragma unroll
    for (int k = 0; k < 16; ++k) {
      float4 a4 = *(const float4*)&As[k][ty * 4];
      float4 b4 = *(const float4*)&Bs[k][tx * 4];
      float a_[4] = {a4.x, a4.y, a4.z, a4.w};
      float b_[4] = {b4.x, b4.y, b4.z, b4.w};
#pragma unroll
      for (int i = 0; i < 4; ++i)
#pragma unroll
        for (int j = 0; j < 4; ++j) acc[i][j] += a_[i] * b_[j];
    }
    __syncthreads();
  }
  float vm[4];
#pragma unroll
  for (int i = 0; i < 4; ++i) vm[i] = v[(size_t)b * NM + m0 + ty * 4 + i];
#pragma unroll
  for (int j = 0; j < 4; ++j) {
    int c = c0 + tx * 4 + j;
    float4 o;
    o.x = vm[0] * acc[0][j];
    o.y = vm[1] * acc[1][j];
    o.z = vm[2] * acc[2][j];
    o.w = vm[3] * acc[3][j];
    *(float4*)(XT + ((size_t)b * NC + c) * NM + m0 + ty * 4) = o;
  }
}

// out_aligned = H + alpha*XT ; out_feat = XT ; partial sums of (H-XT)^2
__global__ __launch_bounds__(256) void finalize_kernel(
    const float* __restrict__ H, const float* __restrict__ XT,
    float* __restrict__ out_aligned, float* __restrict__ out_feat,
    float* __restrict__ partials) {
  const int t = threadIdx.x;
  float s = 0.f;
  for (int i = blockIdx.x * 256 + t; i < OUT_ELEMS / 4; i += 1024 * 256) {
    float4 h = *(const float4*)(H + (size_t)i * 4);
    float4 x = *(const float4*)(XT + (size_t)i * 4);
    float4 o;
    o.x = h.x + ALPHA_C * x.x;
    o.y = h.y + ALPHA_C * x.y;
    o.z = h.z + ALPHA_C * x.z;
    o.w = h.w + ALPHA_C * x.w;
    *(float4*)(out_aligned + (size_t)i * 4) = o;
    out_feat[(size_t)i * 4 + 0] = x.x;  // dest misaligned by 1 float -> scalar
    out_feat[(size_t)i * 4 + 1] = x.y;
    out_feat[(size_t)i * 4 + 2] = x.z;
    out_feat[(size_t)i * 4 + 3] = x.w;
    float dx = h.x - x.x, dy = h.y - x.y, dz = h.z - x.z, dw = h.w - x.w;
    s += dx * dx + dy * dy + dz * dz + dw * dw;
  }
  s = waveSum(s);
  __shared__ float ws_[4];
  if ((t & 63) == 0) ws_[t >> 6] = s;
  __syncthreads();
  if (t == 0) partials[blockIdx.x] = ws_[0] + ws_[1] + ws_[2] + ws_[3];
}

__global__ __launch_bounds__(256) void lot_kernel(
    const float* __restrict__ partials, float* __restrict__ out_lot) {
  float s = 0.f;
  for (int i = threadIdx.x; i < 1024; i += 256) s += partials[i];
  s = waveSum(s);
  __shared__ float ws_[4];
  if ((threadIdx.x & 63) == 0) ws_[threadIdx.x >> 6] = s;
  __syncthreads();
  if (threadIdx.x == 0)
    out_lot[0] = (ws_[0] + ws_[1] + ws_[2] + ws_[3]) / (float)OUT_ELEMS;
}

extern "C" void kernel_launch(void* const* d_in, const int* in_sizes, int n_in,
                              void* d_out, int out_size, void* d_ws,
                              size_t ws_size, hipStream_t stream) {
  const float* X = (const float*)d_in[0];  // sc (4096,256)
  const float* H = (const float*)d_in[1];  // h_spot (4,256,48,48)
  float* out = (float*)d_out;
  char* ws = (char*)d_ws;

  // workspace layout (bytes)
  unsigned short* K = (unsigned short*)(ws);   // 75,497,472
  float* XT = (float*)(ws + 75497472);         // 9,437,184
  float* x2 = (float*)(ws + 84934656);         // 16,384
  float* y2 = (float*)(ws + 84951040);         // 36,864
  float* u = (float*)(ws + 84987904);          // 65,536
  float* v = (float*)(ws + 85053440);          // 36,864
  float* vsum = (float*)(ws + 85090304);       // 2*4*2304*4 = 73,728
  int* notconv = (int*)(ws + 85164032);        // 32
  float* partials = (float*)(ws + 85164064);   // 4,096
  if (ws_size < (size_t)85168160) return;

  x2_kernel<<<1024, 256, 0, stream>>>(X, x2);
  y2_kernel<<<36, 256, 0, stream>>>(H, y2);
  cost_k_kernel<<<dim3(64, 36, 4), 256, 0, stream>>>(X, H, x2, y2, K);
  init_kernel<<<64, 256, 0, stream>>>(u, vsum, notconv);
  for (int it = 0; it < 200; ++it) {
    const int p = it & 1, q = 1 - p;  // ncPrev slot (it-1)&1 == q; init slot1=1
    vpart_kernel<<<dim3(9, 64, 4), 256, 0, stream>>>(
        K, u, vsum + (size_t)p * 4 * NM, notconv + q * 4, notconv + p * 4);
    uker_kernel<<<dim3(256, 4), 256, 0, stream>>>(
        K, vsum + (size_t)p * 4 * NM, vsum + (size_t)q * 4 * NM, u, v,
        notconv + q * 4, notconv + p * 4);
  }
  xspace_kernel<<<dim3(36, 4, 4), 256, 0, stream>>>(K, X, u, v, XT);
  finalize_kernel<<<1024, 256, 0, stream>>>(H, XT, out, out + OUT_ELEMS + 1,
                                            partials);
  lot_kernel<<<1, 256, 0, stream>>>(partials, out + OUT_ELEMS);
}

// Round 4
// 1226.064 us; speedup vs baseline: 38.7028x; 1.8529x over previous
//
#include <hip/hip_runtime.h>

#define NN 4096
#define NM 2304
#define NC 256
#define OUT_ELEMS 2359296  // 4*256*48*48
#define MAX_IT 100

static constexpr float REG_INV = 0.1f;      // 1/REG
static constexpr float A_VAL = 1.0f / 4096.0f;
static constexpr float B_VAL = 1.0f / 2304.0f;
static constexpr float ALPHA_C = 0.001f;
static constexpr float EPS_CONV = 1e-6f;

typedef __attribute__((ext_vector_type(8))) short bf16x8;
typedef __attribute__((ext_vector_type(4))) float f32x4;

__device__ __forceinline__ float bf2f(unsigned short h) {
  return __uint_as_float(((unsigned int)h) << 16);
}
__device__ __forceinline__ unsigned short f2bf(float f) {
  unsigned int u = __float_as_uint(f);
  unsigned int r = (u + 0x7FFFu + ((u >> 16) & 1u)) >> 16;  // RNE
  return (unsigned short)r;
}
__device__ __forceinline__ float waveSum(float s) {
#pragma unroll
  for (int off = 32; off > 0; off >>= 1) s += __shfl_xor(s, off);
  return s;
}

// x2[n] = sum_c X[n][c]^2 ; one wave per row
__global__ __launch_bounds__(256) void x2_kernel(const float* __restrict__ X,
                                                 float* __restrict__ x2) {
  int wid = threadIdx.x >> 6, lane = threadIdx.x & 63;
  int row = blockIdx.x * 4 + wid;
  float4 v = *(const float4*)(X + (size_t)row * NC + lane * 4);
  float s = v.x * v.x + v.y * v.y + v.z * v.z + v.w * v.w;
  s = waveSum(s);
  if (lane == 0) x2[row] = s;
}

// y2[b][m] = sum_c H[b][c][m]^2
__global__ __launch_bounds__(256) void y2_kernel(const float* __restrict__ H,
                                                 float* __restrict__ y2) {
  int gid = blockIdx.x * 256 + threadIdx.x;  // grid 36 -> 9216
  int b = gid / NM, m = gid % NM;
  const float* p = H + (size_t)b * NC * NM + m;
  float s = 0.f;
#pragma unroll 4
  for (int c = 0; c < NC; ++c) {
    float t = p[(size_t)c * NM];
    s += t * t;
  }
  y2[gid] = s;
}

// Xbf = bf16(X), elementwise; grid 1024
__global__ __launch_bounds__(256) void prep_xbf(const float* __restrict__ X,
                                                unsigned short* __restrict__ Xbf) {
  size_t i = blockIdx.x * 256 + threadIdx.x;
  float4 xv = *(const float4*)(X + i * 4);
  ushort4 o = {f2bf(xv.x), f2bf(xv.y), f2bf(xv.z), f2bf(xv.w)};
  *(ushort4*)(Xbf + i * 4) = o;
}

// HT[b][m][c] = bf16(H[b][c][m]); grid (72, 8, 4), 32x32 LDS tile transpose
__global__ __launch_bounds__(256) void prep_ht(const float* __restrict__ H,
                                               unsigned short* __restrict__ HT) {
  __shared__ unsigned short tile[32][34];
  const int b = blockIdx.z;
  const int mt = blockIdx.x * 32, ct = blockIdx.y * 32;
  const int t = threadIdx.x;
#pragma unroll
  for (int p = 0; p < 4; ++p) {
    int c = ct + p * 8 + (t >> 5);
    tile[t & 31][p * 8 + (t >> 5)] = f2bf(H[((size_t)b * NC + c) * NM + mt + (t & 31)]);
  }
  __syncthreads();
#pragma unroll
  for (int p = 0; p < 4; ++p) {
    int mloc = p * 8 + (t >> 5);
    HT[((size_t)b * NM + mt + mloc) * NC + ct + (t & 31)] = tile[mloc][t & 31];
  }
}

// XuT[b][c][n] = bf16(u[b][n]*X[n][c]); grid (128, 8, 4)
__global__ __launch_bounds__(256) void prep_xut(const float* __restrict__ X,
                                                const float* __restrict__ u,
                                                unsigned short* __restrict__ XuT) {
  __shared__ unsigned short tile[32][34];
  const int b = blockIdx.z;
  const int nt = blockIdx.x * 32, ct = blockIdx.y * 32;
  const int t = threadIdx.x;
#pragma unroll
  for (int p = 0; p < 4; ++p) {
    int nloc = p * 8 + (t >> 5);
    float uu = u[b * NN + nt + nloc];
    tile[nloc][t & 31] = f2bf(uu * X[(size_t)(nt + nloc) * NC + ct + (t & 31)]);
  }
  __syncthreads();
#pragma unroll
  for (int p = 0; p < 4; ++p) {
    int cloc = p * 8 + (t >> 5);
    XuT[((size_t)b * NC + ct + cloc) * NN + nt + (t & 31)] = tile[t & 31][cloc];
  }
}

// u = A_VAL, vsum[parity 0] = 0, notconv = 1
__global__ __launch_bounds__(256) void init_kernel(float* __restrict__ u,
                                                   float* __restrict__ vsum0,
                                                   int* __restrict__ notconv) {
  int gid = blockIdx.x * 256 + threadIdx.x;  // grid 64 -> 16384
  u[gid] = A_VAL;
  if (gid < NM * 4) vsum0[gid] = 0.f;
  if (gid < 8) notconv[gid] = 1;
}

// MFMA cost+K kernel: tile 128n x 128m, 4 waves (2x2), K-dim = 256 c in steps of 32.
// Writes K[b][n][m] bf16 and KT[b][m][n] bf16.
__global__ __launch_bounds__(256) void cost_k_mfma(
    const unsigned short* __restrict__ Xbf, const unsigned short* __restrict__ HT,
    const float* __restrict__ x2, const float* __restrict__ y2,
    unsigned short* __restrict__ K, unsigned short* __restrict__ KT) {
  __shared__ unsigned short As[128][40];
  __shared__ unsigned short Bs[128][40];
  const int b = blockIdx.z;
  const int n0 = blockIdx.x * 128, m0 = blockIdx.y * 128;
  const int t = threadIdx.x, l = t & 63, w = t >> 6;
  const int wn = (w >> 1) * 64, wm = (w & 1) * 64;
  const int fr = l & 15, fq = l >> 4;
  f32x4 zero = {0.f, 0.f, 0.f, 0.f};
  f32x4 acc[4][4];
#pragma unroll
  for (int i = 0; i < 4; ++i)
#pragma unroll
    for (int j = 0; j < 4; ++j) acc[i][j] = zero;

  for (int c0 = 0; c0 < NC; c0 += 32) {
#pragma unroll
    for (int i = 0; i < 2; ++i) {
      int idx = t + i * 256;
      int row = idx >> 2, ck = idx & 3;
      float4 av = *(const float4*)(Xbf + (size_t)(n0 + row) * NC + c0 + ck * 8);
      *(float4*)(&As[row][ck * 8]) = av;
      float4 bv = *(const float4*)(HT + ((size_t)b * NM + m0 + row) * NC + c0 + ck * 8);
      *(float4*)(&Bs[row][ck * 8]) = bv;
    }
    __syncthreads();
    bf16x8 a[4], bb[4];
#pragma unroll
    for (int f = 0; f < 4; ++f) {
      a[f] = *(const bf16x8*)(&As[wn + f * 16 + fr][fq * 8]);
      bb[f] = *(const bf16x8*)(&Bs[wm + f * 16 + fr][fq * 8]);
    }
#pragma unroll
    for (int i = 0; i < 4; ++i)
#pragma unroll
      for (int j = 0; j < 4; ++j)
        acc[i][j] = __builtin_amdgcn_mfma_f32_16x16x32_bf16(a[i], bb[j], acc[i][j], 0, 0, 0);
    __syncthreads();
  }
#pragma unroll
  for (int fi = 0; fi < 4; ++fi) {
    int nb = n0 + wn + fi * 16 + fq * 4;
    float4 x2v = *(const float4*)(x2 + nb);
    float x2a[4] = {x2v.x, x2v.y, x2v.z, x2v.w};
#pragma unroll
    for (int fj = 0; fj < 4; ++fj) {
      int m = m0 + wm + fj * 16 + fr;
      float y2v = y2[b * NM + m];
      unsigned short kk[4];
#pragma unroll
      for (int r = 0; r < 4; ++r) {
        float cost = fmaxf(x2a[r] + y2v - 2.0f * acc[fi][fj][r], 0.0f);
        kk[r] = f2bf(__expf(-cost * REG_INV));
      }
#pragma unroll
      for (int r = 0; r < 4; ++r)
        K[((size_t)b * NN + nb + r) * NM + m] = kk[r];
      ushort4 kt4 = {kk[0], kk[1], kk[2], kk[3]};
      *(ushort4*)(KT + ((size_t)b * NM + m) * NN + nb) = kt4;
    }
  }
}

// vsumC[b][m] += sum_{n in 256-chunk} K[b][n][m]*u[b][n]; grid (9, 16, 4)
__global__ __launch_bounds__(256) void vpart_kernel(
    const unsigned short* __restrict__ K, const float* __restrict__ u,
    float* __restrict__ vsumC, const int* __restrict__ ncPrev,
    int* __restrict__ ncZero) {
  const int b = blockIdx.z;
  if (blockIdx.x == 0 && blockIdx.y == 0 && threadIdx.x == 0) ncZero[b] = 0;
  if (ncPrev[b] == 0) return;
  const int mg = blockIdx.x;  // 0..8 (m-group of 256)
  const int ch = blockIdx.y;  // 0..15 (n-chunk of 256)
  const int t = threadIdx.x, l = t & 63, w = t >> 6;
  __shared__ float uS[256];
  __shared__ __align__(16) float red[4][64][4];
  uS[t] = u[b * NN + ch * 256 + t];
  __syncthreads();
  const unsigned short* Kp =
      K + ((size_t)b * NN + ch * 256) * NM + mg * 256 + l * 4;
  float4 acc = {0.f, 0.f, 0.f, 0.f};
#pragma unroll 8
  for (int i = 0; i < 64; ++i) {
    int n = i * 4 + w;
    ushort4 kk = *(const ushort4*)(Kp + (size_t)n * NM);
    float uu = uS[n];
    acc.x += bf2f(kk.x) * uu;
    acc.y += bf2f(kk.y) * uu;
    acc.z += bf2f(kk.z) * uu;
    acc.w += bf2f(kk.w) * uu;
  }
  *(float4*)red[w][l] = acc;
  __syncthreads();
  if (w == 0) {
    float4 a0 = *(float4*)red[0][l];
    float4 a1 = *(float4*)red[1][l];
    float4 a2 = *(float4*)red[2][l];
    float4 a3 = *(float4*)red[3][l];
    float* dst = vsumC + (size_t)b * NM + mg * 256 + l * 4;
    atomicAdd(dst + 0, a0.x + a1.x + a2.x + a3.x);
    atomicAdd(dst + 1, a0.y + a1.y + a2.y + a3.y);
    atomicAdd(dst + 2, a0.z + a1.z + a2.z + a3.z);
    atomicAdd(dst + 3, a0.w + a1.w + a2.w + a3.w);
  }
}

// u[b][n] = A_VAL / sum_m K[b][n][m]*(B_VAL/vsumC[b][m]); grid (128, 4), 32 rows/block
__global__ __launch_bounds__(256) void uker_kernel(
    const unsigned short* __restrict__ K, const float* __restrict__ vsumC,
    float* __restrict__ vsumN, float* __restrict__ u, float* __restrict__ v,
    const int* __restrict__ ncPrev, int* __restrict__ ncSet) {
  const int b = blockIdx.y;
  if (ncPrev[b] == 0) return;
  const int t = threadIdx.x, l = t & 63, w = t >> 6;
  __shared__ __align__(16) float vS[NM];
  for (int i = t; i < NM; i += 256) {
    float val = B_VAL / vsumC[(size_t)b * NM + i];
    vS[i] = val;
    if (blockIdx.x == 0) v[b * NM + i] = val;
    if (blockIdx.x == 1) vsumN[(size_t)b * NM + i] = 0.f;
  }
  __syncthreads();
  float4 vv[9];
#pragma unroll
  for (int kk = 0; kk < 9; ++kk) vv[kk] = *(const float4*)&vS[kk * 256 + l * 4];
#pragma unroll 1
  for (int r = 0; r < 8; ++r) {
    const int n = blockIdx.x * 32 + w * 8 + r;
    const unsigned short* Kp = K + ((size_t)b * NN + n) * NM + l * 4;
    float s = 0.f;
#pragma unroll
    for (int kk = 0; kk < 9; ++kk) {
      ushort4 h = *(const ushort4*)(Kp + kk * 256);
      s += bf2f(h.x) * vv[kk].x + bf2f(h.y) * vv[kk].y +
           bf2f(h.z) * vv[kk].z + bf2f(h.w) * vv[kk].w;
    }
    s = waveSum(s);
    if (l == 0) {
      float uo = u[b * NN + n];
      float un = A_VAL / s;
      u[b * NN + n] = un;
      if (fabsf(un - uo) > EPS_CONV * uo) ncSet[b] = 1;
    }
  }
}

// XT[b][c][m] = v[m] * sum_n XuT[c][n]*KT[m][n]; MFMA, tile 64c x 64m, BK=64
__global__ __launch_bounds__(256) void xspace_mfma(
    const unsigned short* __restrict__ XuT, const unsigned short* __restrict__ KT,
    const float* __restrict__ v, float* __restrict__ XT) {
  __shared__ unsigned short As[64][72];
  __shared__ unsigned short Bs[64][72];
  const int b = blockIdx.z;
  const int c0 = blockIdx.x * 64, m0 = blockIdx.y * 64;
  const int t = threadIdx.x, l = t & 63, w = t >> 6;
  const int wc = (w >> 1) * 32, wm = (w & 1) * 32;
  const int fr = l & 15, fq = l >> 4;
  f32x4 zero = {0.f, 0.f, 0.f, 0.f};
  f32x4 acc[2][2];
#pragma unroll
  for (int i = 0; i < 2; ++i)
#pragma unroll
    for (int j = 0; j < 2; ++j) acc[i][j] = zero;

  for (int k0 = 0; k0 < NN; k0 += 64) {
#pragma unroll
    for (int i = 0; i < 2; ++i) {
      int idx = t + i * 256;
      int row = idx >> 3, ck = idx & 7;
      float4 av = *(const float4*)(XuT + ((size_t)b * NC + c0 + row) * NN + k0 + ck * 8);
      *(float4*)(&As[row][ck * 8]) = av;
      float4 bv = *(const float4*)(KT + ((size_t)b * NM + m0 + row) * NN + k0 + ck * 8);
      *(float4*)(&Bs[row][ck * 8]) = bv;
    }
    __syncthreads();
    bf16x8 a[2][2], bb[2][2];
#pragma unroll
    for (int f = 0; f < 2; ++f)
#pragma unroll
      for (int ks = 0; ks < 2; ++ks) {
        a[f][ks] = *(const bf16x8*)(&As[wc + f * 16 + fr][ks * 32 + fq * 8]);
        bb[f][ks] = *(const bf16x8*)(&Bs[wm + f * 16 + fr][ks * 32 + fq * 8]);
      }
#pragma unroll
    for (int ks = 0; ks < 2; ++ks)
#pragma unroll
      for (int i = 0; i < 2; ++i)
#pragma unroll
        for (int j = 0; j < 2; ++j)
          acc[i][j] = __builtin_amdgcn_mfma_f32_16x16x32_bf16(a[i][ks], bb[j][ks], acc[i][j], 0, 0, 0);
    __syncthreads();
  }
#pragma unroll
  for (int fj = 0; fj < 2; ++fj) {
    int m = m0 + wm + fj * 16 + fr;
    float vm = v[(size_t)b * NM + m];
#pragma unroll
    for (int fi = 0; fi < 2; ++fi) {
      int cb = c0 + wc + fi * 16 + fq * 4;
#pragma unroll
      for (int r = 0; r < 4; ++r)
        XT[((size_t)b * NC + cb + r) * NM + m] = vm * acc[fi][fj][r];
    }
  }
}

// out_aligned = H + alpha*XT ; out_feat = XT ; partial sums of (H-XT)^2
__global__ __launch_bounds__(256) void finalize_kernel(
    const float* __restrict__ H, const float* __restrict__ XT,
    float* __restrict__ out_aligned, float* __restrict__ out_feat,
    float* __restrict__ partials) {
  const int t = threadIdx.x;
  float s = 0.f;
  for (int i = blockIdx.x * 256 + t; i < OUT_ELEMS / 4; i += 1024 * 256) {
    float4 h = *(const float4*)(H + (size_t)i * 4);
    float4 x = *(const float4*)(XT + (size_t)i * 4);
    float4 o;
    o.x = h.x + ALPHA_C * x.x;
    o.y = h.y + ALPHA_C * x.y;
    o.z = h.z + ALPHA_C * x.z;
    o.w = h.w + ALPHA_C * x.w;
    *(float4*)(out_aligned + (size_t)i * 4) = o;
    out_feat[(size_t)i * 4 + 0] = x.x;  // dest misaligned by 1 float -> scalar
    out_feat[(size_t)i * 4 + 1] = x.y;
    out_feat[(size_t)i * 4 + 2] = x.z;
    out_feat[(size_t)i * 4 + 3] = x.w;
    float dx = h.x - x.x, dy = h.y - x.y, dz = h.z - x.z, dw = h.w - x.w;
    s += dx * dx + dy * dy + dz * dz + dw * dw;
  }
  s = waveSum(s);
  __shared__ float ws_[4];
  if ((t & 63) == 0) ws_[t >> 6] = s;
  __syncthreads();
  if (t == 0) partials[blockIdx.x] = ws_[0] + ws_[1] + ws_[2] + ws_[3];
}

__global__ __launch_bounds__(256) void lot_kernel(
    const float* __restrict__ partials, float* __restrict__ out_lot) {
  float s = 0.f;
  for (int i = threadIdx.x; i < 1024; i += 256) s += partials[i];
  s = waveSum(s);
  __shared__ float ws_[4];
  if ((threadIdx.x & 63) == 0) ws_[threadIdx.x >> 6] = s;
  __syncthreads();
  if (threadIdx.x == 0)
    out_lot[0] = (ws_[0] + ws_[1] + ws_[2] + ws_[3]) / (float)OUT_ELEMS;
}

extern "C" void kernel_launch(void* const* d_in, const int* in_sizes, int n_in,
                              void* d_out, int out_size, void* d_ws,
                              size_t ws_size, hipStream_t stream) {
  const float* X = (const float*)d_in[0];  // sc (4096,256)
  const float* H = (const float*)d_in[1];  // h_spot (4,256,48,48)
  float* out = (float*)d_out;
  char* ws = (char*)d_ws;

  // workspace layout (bytes)
  unsigned short* K = (unsigned short*)(ws);              // 75,497,472
  unsigned short* KT = (unsigned short*)(ws + 75497472);  // 75,497,472
  float* XT = (float*)(ws + 150994944);                   // 9,437,184
  // aliases inside XT region (dead before xspace writes XT):
  unsigned short* Xbf = (unsigned short*)(ws + 150994944);          // 2,097,152
  unsigned short* HT = (unsigned short*)(ws + 150994944 + 2097152); // 4,718,592
  float* vsum = (float*)(ws + 150994944 + 6815744);                 // 73,728
  // alias inside K (dead after the loop):
  unsigned short* XuT = (unsigned short*)(ws);                      // 8,388,608
  float* x2 = (float*)(ws + 160432128);        // 16,384
  float* y2 = (float*)(ws + 160448512);        // 36,864
  float* u = (float*)(ws + 160485376);         // 65,536
  float* v = (float*)(ws + 160550912);         // 36,864
  int* notconv = (int*)(ws + 160587776);       // 32
  float* partials = (float*)(ws + 160587808);  // 4,096
  if (ws_size < (size_t)160591904) return;

  x2_kernel<<<1024, 256, 0, stream>>>(X, x2);
  y2_kernel<<<36, 256, 0, stream>>>(H, y2);
  prep_xbf<<<1024, 256, 0, stream>>>(X, Xbf);
  prep_ht<<<dim3(72, 8, 4), 256, 0, stream>>>(H, HT);
  cost_k_mfma<<<dim3(32, 18, 4), 256, 0, stream>>>(Xbf, HT, x2, y2, K, KT);
  init_kernel<<<64, 256, 0, stream>>>(u, vsum, notconv);
  for (int it = 0; it < MAX_IT; ++it) {
    const int p = it & 1, q = 1 - p;
    vpart_kernel<<<dim3(9, 16, 4), 256, 0, stream>>>(
        K, u, vsum + (size_t)p * 4 * NM, notconv + q * 4, notconv + p * 4);
    uker_kernel<<<dim3(128, 4), 256, 0, stream>>>(
        K, vsum + (size_t)p * 4 * NM, vsum + (size_t)q * 4 * NM, u, v,
        notconv + q * 4, notconv + p * 4);
  }
  prep_xut<<<dim3(128, 8, 4), 256, 0, stream>>>(X, u, XuT);
  xspace_mfma<<<dim3(4, 36, 4), 256, 0, stream>>>(XuT, KT, v, XT);
  finalize_kernel<<<1024, 256, 0, stream>>>(H, XT, out, out + OUT_ELEMS + 1,
                                            partials);
  lot_kernel<<<1, 256, 0, stream>>>(partials, out + OUT_ELEMS);
}